// Round 10
// baseline (1597.113 us; speedup 1.0000x reference)
//
#include <hip/hip_runtime.h>
#include <hip/hip_bf16.h>

#define N_ROWS 131072
#define DIM    768
#define K_C    2000
#define K_PAD  2048
#define TAU    0.2f
#define LISTCAP 8192

typedef _Float16 f16;
typedef _Float16 f16x4 __attribute__((ext_vector_type(4)));
typedef _Float16 f16x8 __attribute__((ext_vector_type(8)));
typedef float    f32x4 __attribute__((ext_vector_type(4)));

// ---- workspace layout (bytes) ----
#define OFF_CN   6291456    // cn   [2048] f32
#define OFF_XN   6299648    // xn   [131072] f32
#define OFF_PMIN 6823936    // pmin [16][131072] f32
#define OFF_PSEC 15212544   // psec [16][131072] f32
#define OFF_PIDX 23601152   // pidx [16][131072] i32
#define OFF_CNT  31989760   // counter
#define OFF_LIST 31990016   // list [8192] i32
#define OFF_CN64 32022784   // cn64 [2048] f64
#define OFF_XH   32039168   // xh [131072][768] f16

static __device__ __forceinline__ void gload16(const void* g, void* l) {
  __builtin_amdgcn_global_load_lds(
      (const __attribute__((address_space(1))) unsigned int*)g,
      (__attribute__((address_space(3))) unsigned int*)l, 16, 0, 0);
}

// K1a: fp32 c_norm (np axis-0 sequential order) + fp64 c_norm for recheck.
__global__ void prep_cn(const float* __restrict__ cent, float* __restrict__ cn,
                        double* __restrict__ cn64) {
#pragma clang fp contract(off)
  int k = blockIdx.x * 256 + threadIdx.x;  // 0..2047
  float s = 0.0f;
  double s64 = 0.0;
  for (int d = 0; d < DIM; ++d) {
    float c = (k < K_C) ? cent[d * K_C + k] : 0.0f;
    float sq = c * c;
    s = s + sq;
    s64 += (double)c * (double)c;
  }
  cn[k] = (k < K_C) ? s : INFINITY;
  cn64[k] = (k < K_C) ? s64 : (double)INFINITY;
}

// K1b: centroid transpose to f16 via 64x64 LDS tile.
__global__ __launch_bounds__(256) void prep_ct(const float* __restrict__ cent,
                                               f16* __restrict__ cTh) {
  __shared__ float ld[64][65];
  int k0 = blockIdx.x * 64;  // 32 blocks
  int d0 = blockIdx.y * 64;  // 12 blocks
  int tid = threadIdx.x;
#pragma unroll
  for (int it = 0; it < 16; ++it) {
    int idx = it * 256 + tid;
    int dd = idx >> 6, kk = idx & 63;
    int k = k0 + kk;
    ld[dd][kk] = (k < K_C) ? cent[(size_t)(d0 + dd) * K_C + k] : 0.0f;
  }
  __syncthreads();
#pragma unroll
  for (int it = 0; it < 16; ++it) {
    int idx = it * 256 + tid;
    int kk = idx >> 6, dd = idx & 63;
    cTh[(size_t)(k0 + kk) * DIM + d0 + dd] = (f16)ld[dd][kk];
  }
}

// K2: x_norm (numpy FLOAT_pairwise_sum(768) scalar semantics) fused with
// x -> f16.
__global__ __launch_bounds__(256) void xnorm_prepx(const float* __restrict__ x,
                                                   float* __restrict__ xn,
                                                   f16* __restrict__ xh) {
#pragma clang fp contract(off)
  __shared__ __align__(16) float buf[16 * DIM];  // 48 KB, 16 rows
  int row0 = blockIdx.x * 16;
  int tid = threadIdx.x;
  const f32x4* src = (const f32x4*)(x + (size_t)row0 * DIM);
  f32x4* dst = (f32x4*)buf;
#pragma unroll
  for (int c = 0; c < 12; ++c) {
    f32x4 v = src[c * 256 + tid];
    dst[c * 256 + tid] = v;
    f16x4 hv;
#pragma unroll
    for (int j = 0; j < 4; ++j) hv[j] = (f16)v[j];
    *(f16x4*)(xh + (size_t)row0 * DIM + (size_t)(c * 256 + tid) * 4) = hv;
  }
  __syncthreads();
  int w = tid >> 6, lane = tid & 63;
  int b = lane >> 3, j = lane & 7;
#pragma unroll
  for (int rr = 0; rr < 4; ++rr) {
    int r = w * 4 + rr;
    const float* a = buf + r * DIM + 96 * b + j;
    float v0 = a[0];
    float acc = v0 * v0;
#pragma unroll
    for (int t = 1; t < 12; ++t) {
      float q = a[8 * t];
      float s = q * q;
      acc = acc + s;
    }
    float v = acc;
    { float o = __shfl_xor(v, 1);  v = v + o; }
    { float o = __shfl_xor(v, 2);  v = v + o; }
    { float o = __shfl_xor(v, 4);  v = v + o; }
    { float o = __shfl_xor(v, 8);  v = v + o; }
    { float o = __shfl_xor(v, 16); v = v + o; }
    { float o = __shfl_xor(v, 32); v = v + o; }
    if (lane == 0) xn[row0 + r] = v;
  }
}

// K3: f16 MFMA GEMM + fused argmin. A-fragments loaded DIRECT global->reg
// (the 16x16x32 A frag is lane-contiguous 16B: row*1536B + ksel*16B — no
// LDS roundtrip, halves LDS traffic). B staged via global_load_lds,
// double-buffered 2x16KB (r7-proven 128B-row slot^=row&7 swizzle, 0
// conflicts), counted vmcnt(4) (B loads only at the wait points; compiler
// inserts exact waits for its tracked A loads). 32 KB LDS -> 3 blocks/CU.
#define STAGE_B(bufb, ktv)                                                     \
  do {                                                                         \
    _Pragma("unroll") for (int i_ = 0; i_ < 4; ++i_) {                         \
      int q_ = w * 4 + i_;                                                     \
      int s0_ = q_ * 1024 + lane * 16;                                         \
      int row_ = s0_ >> 7;                                                     \
      int sl_ = ((s0_ >> 4) & 7) ^ (row_ & 7);                                 \
      size_t gb_ = (size_t)(pb * 128 + row_) * DIM + (ktv) * 64 + sl_ * 8;     \
      gload16(cTh + gb_, ldsb + (bufb) + q_ * 1024);                           \
    }                                                                          \
  } while (0)

__global__ __launch_bounds__(256, 3) void kmeans_main(
    const f16* __restrict__ xh, const f16* __restrict__ cTh,
    const float* __restrict__ cn, const float* __restrict__ xn,
    float* __restrict__ pmin, float* __restrict__ psec,
    int* __restrict__ pidx) {
  __shared__ __align__(16) f16 lds[16384];  // 32 KiB: B double-buffer only
  char* ldsb = (char*)lds;

  int d0 = blockIdx.x;
  int g  = (d0 & 7) * 2048 + (d0 >> 3);  // XCD-grouped
  int pb = g & 15;
  int rb = g >> 4;

  int tid  = threadIdx.x;
  int w    = tid >> 6;
  int lane = tid & 63;
  int wrow = (w >> 1) * 64;
  int wcol = (w & 1) * 64;

  int rsel = lane & 15;
  int ksel = lane >> 4;
  int rs0 = ((ksel ^ (rsel & 7))) << 4;        // k32=0 B slot byte-offset
  int rs1 = (((4 + ksel) ^ (rsel & 7))) << 4;  // k32=1

  // per-lane A fragment base: row = rb*128 + wrow + rsel, k = ksel*8
  const char* aptr = (const char*)xh +
      ((size_t)(rb * 128 + wrow + rsel) * DIM + (size_t)ksel * 8) * 2;

  f32x4 acc[4][4] = {};

  STAGE_B(0, 0);
  STAGE_B(16384, 1);

  for (int kt = 0; kt < 12; ++kt) {
    int bufb = (kt & 1) * 16384;
    if (kt < 11) {
      asm volatile("s_waitcnt vmcnt(4)" ::: "memory");  // B tile kt landed
    } else {
      asm volatile("s_waitcnt vmcnt(0)" ::: "memory");
    }
    __builtin_amdgcn_sched_barrier(0);
    __builtin_amdgcn_s_barrier();
    __builtin_amdgcn_sched_barrier(0);

    // A frags: direct global->reg (compiler-tracked waits before MFMA)
    f16x8 ah[2][4], bh[2][4];
#pragma unroll
    for (int m = 0; m < 4; ++m) {
      const char* ab = aptr + m * 24576;  // m*16 rows * 1536 B
      ah[0][m] = *(const f16x8*)(ab);
      ah[1][m] = *(const f16x8*)(ab + 64);  // k += 32 elems
    }
    // B frags from LDS
#pragma unroll
    for (int n = 0; n < 4; ++n) {
      int rbase = bufb + (wcol + n * 16 + rsel) * 128;
      bh[0][n] = *(const f16x8*)(ldsb + rbase + rs0);
      bh[1][n] = *(const f16x8*)(ldsb + rbase + rs1);
    }
    __builtin_amdgcn_sched_barrier(0);
    asm volatile("s_waitcnt lgkmcnt(0)" ::: "memory");  // B frags in VGPRs
    __builtin_amdgcn_sched_barrier(0);
    __builtin_amdgcn_s_barrier();  // all waves done reading buf[cur]
    __builtin_amdgcn_sched_barrier(0);

    if (kt < 10) STAGE_B(bufb, kt + 2);  // in flight across next barriers

    __builtin_amdgcn_s_setprio(1);
#pragma unroll
    for (int k32 = 0; k32 < 2; ++k32)
#pragma unroll
      for (int m = 0; m < 4; ++m)
#pragma unroll
        for (int n = 0; n < 4; ++n)
          acc[m][n] = __builtin_amdgcn_mfma_f32_16x16x32_f16(
              ah[k32][m], bh[k32][n], acc[m][n], 0, 0, 0);
    __builtin_amdgcn_s_setprio(0);

    aptr += 128;  // advance 64 k-elems
  }

  __syncthreads();  // drain; LDS reused below
  float* lv = (float*)lds;                 // [2][128]
  float* lsv = (float*)lds + 256;          // [2][128]
  int*   li = (int*)((float*)lds + 512);   // [2][128]

  int colbase = pb * 128 + wcol + rsel;
  float cnv[4];
#pragma unroll
  for (int n = 0; n < 4; ++n) cnv[n] = cn[colbase + n * 16];
  int g4 = ksel * 4;

#pragma unroll
  for (int m = 0; m < 4; ++m) {
#pragma unroll
    for (int j = 0; j < 4; ++j) {
      int trow = wrow + m * 16 + g4 + j;
      float xv = xn[rb * 128 + trow];
      float v1 = 0.0f, v2 = INFINITY;
      int i1 = 0;
#pragma unroll
      for (int n = 0; n < 4; ++n) {
        float dd = (xv - 2.0f * acc[m][n][j]) + cnv[n];
        int ci = colbase + n * 16;
        if (n == 0) { v1 = dd; i1 = ci; }
        else if (dd < v1) { v2 = v1; v1 = dd; i1 = ci; }
        else { v2 = fminf(v2, dd); }
      }
#pragma unroll
      for (int off = 1; off < 16; off <<= 1) {
        float ov1 = __shfl_xor(v1, off);
        float ov2 = __shfl_xor(v2, off);
        int oi1 = __shfl_xor(i1, off);
        if (ov1 < v1 || (ov1 == v1 && oi1 < i1)) {
          v2 = fminf(v1, ov2); v1 = ov1; i1 = oi1;
        } else {
          v2 = fminf(v2, ov1);
        }
      }
      if ((lane & 15) == 0) {
        lv[(w & 1) * 128 + trow] = v1;
        lsv[(w & 1) * 128 + trow] = v2;
        li[(w & 1) * 128 + trow] = i1;
      }
    }
  }
  __syncthreads();
  if (tid < 128) {
    float a1 = lv[tid], a2 = lsv[tid];
    int aj = li[tid];
    float b1 = lv[128 + tid], b2 = lsv[128 + tid];
    int bj = li[128 + tid];
    float v1, v2; int i1;
    if (b1 < a1 || (b1 == a1 && bj < aj)) { v1 = b1; i1 = bj; v2 = fminf(b2, a1); }
    else { v1 = a1; i1 = aj; v2 = fminf(a2, b1); }
    size_t o = (size_t)pb * N_ROWS + rb * 128 + tid;
    pmin[o] = v1;
    psec[o] = v2;
    pidx[o] = i1;
  }
}

// K4: merge 16 panel triples; flag ambiguous rows (margin < TAU).
__global__ void merge_detect(const float* __restrict__ pmin,
                             const float* __restrict__ psec,
                             const int* __restrict__ pidx, int* __restrict__ out,
                             int* __restrict__ list, int* __restrict__ counter) {
  int n = blockIdx.x * 256 + threadIdx.x;
  float v1 = INFINITY, v2 = INFINITY;
  int i1 = 0x7fffffff;
  for (int p = 0; p < 16; ++p) {
    float a1 = pmin[(size_t)p * N_ROWS + n];
    float a2 = psec[(size_t)p * N_ROWS + n];
    int aj = pidx[(size_t)p * N_ROWS + n];
    if (a1 < v1 || (a1 == v1 && aj < i1)) {
      v2 = fminf(v1, a2); v1 = a1; i1 = aj;
    } else {
      v2 = fminf(v2, a1);
    }
  }
  out[n] = i1;
  if (v2 - v1 < TAU) {
    int idx = atomicAdd(counter, 1);
    if (idx < LISTCAP) list[idx] = n;
  }
}

// K5: float64 exact recheck, BATCH-4 rows per block (cent read once per 4
// rows: L2 traffic /4). 32 NAMED f64 accumulators (rule #20: named scalars
// stay in VGPRs; r6's array+branch form went to scratch).
#define ACCS(R) \
  double a##R##0 = 0, a##R##1 = 0, a##R##2 = 0, a##R##3 = 0, \
         a##R##4 = 0, a##R##5 = 0, a##R##6 = 0, a##R##7 = 0
#define FMAS(R, XV) \
  a##R##0 = fma(XV, c0, a##R##0); a##R##1 = fma(XV, c1, a##R##1); \
  a##R##2 = fma(XV, c2, a##R##2); a##R##3 = fma(XV, c3, a##R##3); \
  a##R##4 = fma(XV, c4, a##R##4); a##R##5 = fma(XV, c5, a##R##5); \
  a##R##6 = fma(XV, c6, a##R##6); a##R##7 = fma(XV, c7, a##R##7)
#define EVAL(R)                                                         \
  {                                                                     \
    double dots[8] = {a##R##0, a##R##1, a##R##2, a##R##3,               \
                      a##R##4, a##R##5, a##R##6, a##R##7};              \
    double bv = (double)INFINITY;                                       \
    int bi = 0x7fffffff;                                                \
    _Pragma("unroll") for (int j = 0; j < 8; ++j) {                     \
      int k = tid + j * 256;                                            \
      if (k < K_C) {                                                    \
        double dd = (xnorms[R] - 2.0 * dots[j]) + cn64[k];              \
        if (dd < bv) { bv = dd; bi = k; }                               \
      }                                                                 \
    }                                                                   \
    rv[tid] = bv; ri[tid] = bi;                                         \
    __syncthreads();                                                    \
    for (int s = 128; s > 0; s >>= 1) {                                 \
      if (tid < s) {                                                    \
        double ov = rv[tid + s];                                        \
        int oi = ri[tid + s];                                           \
        if (ov < rv[tid] || (ov == rv[tid] && oi < ri[tid])) {          \
          rv[tid] = ov; ri[tid] = oi;                                   \
        }                                                               \
      }                                                                 \
      __syncthreads();                                                  \
    }                                                                   \
    if (tid == 0 && (R) < nrows) out[list[b0 + (R)]] = ri[0];           \
    __syncthreads();                                                    \
  }

__global__ __launch_bounds__(256) void exact_recheck64(
    const float* __restrict__ x, const float* __restrict__ cent,
    const double* __restrict__ cn64, const int* __restrict__ list,
    const int* __restrict__ counter, int* __restrict__ out) {
  __shared__ __align__(16) float xrow[4][DIM];  // 12 KB
  __shared__ double rv[256];
  __shared__ int ri[256];
  __shared__ double xnorms[4];
  int cnt = counter[0];
  if (cnt > LISTCAP) cnt = LISTCAP;
  int b0 = blockIdx.x * 4;
  if (b0 >= cnt) return;
  int nrows = cnt - b0;
  if (nrows > 4) nrows = 4;
  int tid = threadIdx.x;
  for (int r = 0; r < 4; ++r) {
    int n = list[b0 + (r < nrows ? r : 0)];
    double part = 0.0;
    for (int d = tid; d < DIM; d += 256) {
      float v = x[(size_t)n * DIM + d];
      xrow[r][d] = v;
      part += (double)v * (double)v;
    }
    rv[tid] = part;
    __syncthreads();
    for (int s = 128; s > 0; s >>= 1) {
      if (tid < s) rv[tid] += rv[tid + s];
      __syncthreads();
    }
    if (tid == 0) xnorms[r] = rv[0];
    __syncthreads();
  }

  int k7 = tid + 1792;
  int k7c = (k7 < K_C) ? k7 : (K_C - 1);
  ACCS(0); ACCS(1); ACCS(2); ACCS(3);
#pragma unroll 2
  for (int d = 0; d < DIM; ++d) {
    const float* cp = cent + (size_t)d * K_C + tid;
    double c0 = cp[0], c1 = cp[256], c2 = cp[512], c3 = cp[768];
    double c4 = cp[1024], c5 = cp[1280], c6 = cp[1536];
    double c7 = cp[k7c - tid];
    double x0 = xrow[0][d], x1 = xrow[1][d];
    double x2 = xrow[2][d], x3 = xrow[3][d];
    FMAS(0, x0); FMAS(1, x1); FMAS(2, x2); FMAS(3, x3);
  }
  EVAL(0) EVAL(1) EVAL(2) EVAL(3)
}

extern "C" void kernel_launch(void* const* d_in, const int* in_sizes, int n_in,
                              void* d_out, int out_size, void* d_ws, size_t ws_size,
                              hipStream_t stream) {
  const float* x = (const float*)d_in[0];
  const float* cent = (const float*)d_in[1];
  char* ws = (char*)d_ws;
  f16* cTh = (f16*)ws;
  float* cn = (float*)(ws + OFF_CN);
  float* xn = (float*)(ws + OFF_XN);
  float* pmin = (float*)(ws + OFF_PMIN);
  float* psec = (float*)(ws + OFF_PSEC);
  int* pidx = (int*)(ws + OFF_PIDX);
  int* counter = (int*)(ws + OFF_CNT);
  int* list = (int*)(ws + OFF_LIST);
  double* cn64 = (double*)(ws + OFF_CN64);
  f16* xh = (f16*)(ws + OFF_XH);

  hipMemsetAsync(counter, 0, 4, stream);
  prep_cn<<<8, 256, 0, stream>>>(cent, cn, cn64);
  prep_ct<<<dim3(32, 12), 256, 0, stream>>>(cent, cTh);
  xnorm_prepx<<<N_ROWS / 16, 256, 0, stream>>>(x, xn, xh);
  kmeans_main<<<16384, 256, 0, stream>>>(xh, cTh, cn, xn, pmin, psec, pidx);
  merge_detect<<<N_ROWS / 256, 256, 0, stream>>>(pmin, psec, pidx, (int*)d_out,
                                                 list, counter);
  exact_recheck64<<<LISTCAP / 4, 256, 0, stream>>>(x, cent, cn64, list, counter,
                                                   (int*)d_out);
}

// Round 11
// 1286.797 us; speedup vs baseline: 1.2412x; 1.2412x over previous
//
#include <hip/hip_runtime.h>
#include <hip/hip_bf16.h>

#define N_ROWS 131072
#define DIM    768
#define K_C    2000
#define K_PAD  2048
#define TAU    0.2f
#define LISTCAP 8192

typedef _Float16 f16;
typedef _Float16 f16x4 __attribute__((ext_vector_type(4)));
typedef _Float16 f16x8 __attribute__((ext_vector_type(8)));
typedef float    f32x4 __attribute__((ext_vector_type(4)));

// ---- workspace layout (bytes) ----
#define OFF_CN   6291456    // cn   [2048] f32
#define OFF_XN   6299648    // xn   [131072] f32
#define OFF_PMIN 6823936    // pmin [16][131072] f32
#define OFF_PSEC 15212544   // psec [16][131072] f32
#define OFF_PIDX 23601152   // pidx [16][131072] i32
#define OFF_CNT  31989760   // counter
#define OFF_LIST 31990016   // list [8192] i32
#define OFF_CN64 32022784   // cn64 [2048] f64
#define OFF_XH   32039168   // xh [131072][768] f16

static __device__ __forceinline__ void gload16(const void* g, void* l) {
  __builtin_amdgcn_global_load_lds(
      (const __attribute__((address_space(1))) unsigned int*)g,
      (__attribute__((address_space(3))) unsigned int*)l, 16, 0, 0);
}

// K1a: c_norm, parallelized 64 blocks x 8-way d-split (was 8 blocks /
// latency-bound ~100us). Summation order differs from np — acceptable:
// fp32 cn only feeds gate margins (tau=0.2 >> 1e-4 order noise); fp64
// cn64 order noise ~1e-13 << true distance gaps.
__global__ __launch_bounds__(256) void prep_cn(const float* __restrict__ cent,
                                               float* __restrict__ cn,
                                               double* __restrict__ cn64) {
#pragma clang fp contract(off)
  __shared__ float pf[8][32];
  __shared__ double pd[8][32];
  int t = threadIdx.x;
  int kk = t & 31;
  int k = blockIdx.x * 32 + kk;
  int p = t >> 5;
  float s = 0.0f;
  double s64 = 0.0;
  for (int d = p * 96; d < p * 96 + 96; ++d) {
    float c = (k < K_C) ? cent[d * K_C + k] : 0.0f;
    float sq = c * c;
    s = s + sq;
    s64 += (double)c * (double)c;
  }
  pf[p][kk] = s;
  pd[p][kk] = s64;
  __syncthreads();
  if (p == 0) {
    float ss = 0.0f;
    double ss64 = 0.0;
#pragma unroll
    for (int q = 0; q < 8; ++q) {
      ss = ss + pf[q][kk];
      ss64 += pd[q][kk];
    }
    cn[k] = (k < K_C) ? ss : INFINITY;
    cn64[k] = (k < K_C) ? ss64 : (double)INFINITY;
  }
}

// K1b: centroid transpose to f16 via 64x64 LDS tile.
__global__ __launch_bounds__(256) void prep_ct(const float* __restrict__ cent,
                                               f16* __restrict__ cTh) {
  __shared__ float ld[64][65];
  int k0 = blockIdx.x * 64;  // 32 blocks
  int d0 = blockIdx.y * 64;  // 12 blocks
  int tid = threadIdx.x;
#pragma unroll
  for (int it = 0; it < 16; ++it) {
    int idx = it * 256 + tid;
    int dd = idx >> 6, kk = idx & 63;
    int k = k0 + kk;
    ld[dd][kk] = (k < K_C) ? cent[(size_t)(d0 + dd) * K_C + k] : 0.0f;
  }
  __syncthreads();
#pragma unroll
  for (int it = 0; it < 16; ++it) {
    int idx = it * 256 + tid;
    int kk = idx >> 6, dd = idx & 63;
    cTh[(size_t)(k0 + kk) * DIM + d0 + dd] = (f16)ld[dd][kk];
  }
}

// K2: x_norm (numpy FLOAT_pairwise_sum(768) scalar semantics) fused with
// x -> f16.
__global__ __launch_bounds__(256) void xnorm_prepx(const float* __restrict__ x,
                                                   float* __restrict__ xn,
                                                   f16* __restrict__ xh) {
#pragma clang fp contract(off)
  __shared__ __align__(16) float buf[16 * DIM];  // 48 KB, 16 rows
  int row0 = blockIdx.x * 16;
  int tid = threadIdx.x;
  const f32x4* src = (const f32x4*)(x + (size_t)row0 * DIM);
  f32x4* dst = (f32x4*)buf;
#pragma unroll
  for (int c = 0; c < 12; ++c) {
    f32x4 v = src[c * 256 + tid];
    dst[c * 256 + tid] = v;
    f16x4 hv;
#pragma unroll
    for (int j = 0; j < 4; ++j) hv[j] = (f16)v[j];
    *(f16x4*)(xh + (size_t)row0 * DIM + (size_t)(c * 256 + tid) * 4) = hv;
  }
  __syncthreads();
  int w = tid >> 6, lane = tid & 63;
  int b = lane >> 3, j = lane & 7;
#pragma unroll
  for (int rr = 0; rr < 4; ++rr) {
    int r = w * 4 + rr;
    const float* a = buf + r * DIM + 96 * b + j;
    float v0 = a[0];
    float acc = v0 * v0;
#pragma unroll
    for (int t = 1; t < 12; ++t) {
      float q = a[8 * t];
      float s = q * q;
      acc = acc + s;
    }
    float v = acc;
    { float o = __shfl_xor(v, 1);  v = v + o; }
    { float o = __shfl_xor(v, 2);  v = v + o; }
    { float o = __shfl_xor(v, 4);  v = v + o; }
    { float o = __shfl_xor(v, 8);  v = v + o; }
    { float o = __shfl_xor(v, 16); v = v + o; }
    { float o = __shfl_xor(v, 32); v = v + o; }
    if (lane == 0) xn[row0 + r] = v;
  }
}

// K3: f16 MFMA GEMM + fused argmin. 2-PHASE pipeline (catalog T3 minimum):
// 1-ahead ping-pong prefetch (stage target = other buffer -> ONE barrier
// per K-step), STAGE issued right after the barrier (HBM latency hides
// under ds_read+MFMA), NO manual lgkmcnt wall — compiler emits fine-grained
// lgkmcnt(N) interleaving ds_read with MFMA. A+B via global_load_lds,
// r7-proven swizzle (128B rows, slot^=row&7, 0 conflicts).
// LDS: A bufs @0/@16384, B bufs @32768/@49152.
#define STAGE(bufb, ktv)                                                       \
  do {                                                                         \
    _Pragma("unroll") for (int i_ = 0; i_ < 4; ++i_) {                         \
      int q_ = w * 4 + i_;                                                     \
      int s0_ = q_ * 1024 + lane * 16;                                         \
      int row_ = s0_ >> 7;                                                     \
      int sl_ = ((s0_ >> 4) & 7) ^ (row_ & 7);                                 \
      size_t ga_ = (size_t)(rb * 128 + row_) * DIM + (ktv) * 64 + sl_ * 8;     \
      size_t gb_ = (size_t)(pb * 128 + row_) * DIM + (ktv) * 64 + sl_ * 8;     \
      gload16(xh + ga_, ldsb + (bufb) + q_ * 1024);                            \
      gload16(cTh + gb_, ldsb + 32768 + (bufb) + q_ * 1024);                   \
    }                                                                          \
  } while (0)

__global__ __launch_bounds__(256, 2) void kmeans_main(
    const f16* __restrict__ xh, const f16* __restrict__ cTh,
    const float* __restrict__ cn, const float* __restrict__ xn,
    float* __restrict__ pmin, float* __restrict__ psec,
    int* __restrict__ pidx) {
  __shared__ __align__(16) f16 lds[32768];  // 64 KiB
  char* ldsb = (char*)lds;

  int d0 = blockIdx.x;
  int g  = (d0 & 7) * 2048 + (d0 >> 3);  // XCD-grouped
  int pb = g & 15;
  int rb = g >> 4;

  int tid  = threadIdx.x;
  int w    = tid >> 6;
  int lane = tid & 63;
  int wrow = (w >> 1) * 64;
  int wcol = (w & 1) * 64;

  int rsel = lane & 15;
  int ksel = lane >> 4;
  int rs0 = ((ksel ^ (rsel & 7))) << 4;        // k32=0 slot byte-offset
  int rs1 = (((4 + ksel) ^ (rsel & 7))) << 4;  // k32=1

  f32x4 acc[4][4] = {};

  STAGE(0, 0);

  for (int kt = 0; kt < 12; ++kt) {
    int bufb = (kt & 1) * 16384;
    // own stage-loads for buf[cur] done; barrier syncs everyone's
    asm volatile("s_waitcnt vmcnt(0)" ::: "memory");
    __builtin_amdgcn_sched_barrier(0);
    __builtin_amdgcn_s_barrier();
    __builtin_amdgcn_sched_barrier(0);

    // prefetch next tile into the OTHER buffer: in flight during the
    // ds_read + MFMA below (safe: all waves' reads of buf^1 finished
    // before they could reach this barrier)
    if (kt < 11) STAGE(bufb ^ 16384, kt + 1);

    f16x8 ah[2][4], bh[2][4];
#pragma unroll
    for (int m = 0; m < 4; ++m) {
      int rbase = bufb + (wrow + m * 16 + rsel) * 128;
      ah[0][m] = *(const f16x8*)(ldsb + rbase + rs0);
      ah[1][m] = *(const f16x8*)(ldsb + rbase + rs1);
    }
#pragma unroll
    for (int n = 0; n < 4; ++n) {
      int rbase = bufb + 32768 + (wcol + n * 16 + rsel) * 128;
      bh[0][n] = *(const f16x8*)(ldsb + rbase + rs0);
      bh[1][n] = *(const f16x8*)(ldsb + rbase + rs1);
    }
    // no manual lgkmcnt(0): compiler emits fine-grained lgkmcnt(N) so
    // first MFMAs start while later ds_reads are still in flight
    __builtin_amdgcn_s_setprio(1);
#pragma unroll
    for (int k32 = 0; k32 < 2; ++k32)
#pragma unroll
      for (int m = 0; m < 4; ++m)
#pragma unroll
        for (int n = 0; n < 4; ++n)
          acc[m][n] = __builtin_amdgcn_mfma_f32_16x16x32_f16(
              ah[k32][m], bh[k32][n], acc[m][n], 0, 0, 0);
    __builtin_amdgcn_s_setprio(0);
  }

  __syncthreads();  // drain; LDS reused below
  float* lv = (float*)lds;                 // [2][128]
  float* lsv = (float*)lds + 256;          // [2][128]
  int*   li = (int*)((float*)lds + 512);   // [2][128]

  int colbase = pb * 128 + wcol + rsel;
  float cnv[4];
#pragma unroll
  for (int n = 0; n < 4; ++n) cnv[n] = cn[colbase + n * 16];
  int g4 = ksel * 4;

#pragma unroll
  for (int m = 0; m < 4; ++m) {
#pragma unroll
    for (int j = 0; j < 4; ++j) {
      int trow = wrow + m * 16 + g4 + j;
      float xv = xn[rb * 128 + trow];
      float v1 = 0.0f, v2 = INFINITY;
      int i1 = 0;
#pragma unroll
      for (int n = 0; n < 4; ++n) {
        float dd = (xv - 2.0f * acc[m][n][j]) + cnv[n];
        int ci = colbase + n * 16;
        if (n == 0) { v1 = dd; i1 = ci; }
        else if (dd < v1) { v2 = v1; v1 = dd; i1 = ci; }
        else { v2 = fminf(v2, dd); }
      }
#pragma unroll
      for (int off = 1; off < 16; off <<= 1) {
        float ov1 = __shfl_xor(v1, off);
        float ov2 = __shfl_xor(v2, off);
        int oi1 = __shfl_xor(i1, off);
        if (ov1 < v1 || (ov1 == v1 && oi1 < i1)) {
          v2 = fminf(v1, ov2); v1 = ov1; i1 = oi1;
        } else {
          v2 = fminf(v2, ov1);
        }
      }
      if ((lane & 15) == 0) {
        lv[(w & 1) * 128 + trow] = v1;
        lsv[(w & 1) * 128 + trow] = v2;
        li[(w & 1) * 128 + trow] = i1;
      }
    }
  }
  __syncthreads();
  if (tid < 128) {
    float a1 = lv[tid], a2 = lsv[tid];
    int aj = li[tid];
    float b1 = lv[128 + tid], b2 = lsv[128 + tid];
    int bj = li[128 + tid];
    float v1, v2; int i1;
    if (b1 < a1 || (b1 == a1 && bj < aj)) { v1 = b1; i1 = bj; v2 = fminf(b2, a1); }
    else { v1 = a1; i1 = aj; v2 = fminf(a2, b1); }
    size_t o = (size_t)pb * N_ROWS + rb * 128 + tid;
    pmin[o] = v1;
    psec[o] = v2;
    pidx[o] = i1;
  }
}

// K4: merge 16 panel triples; flag ambiguous rows (margin < TAU).
__global__ void merge_detect(const float* __restrict__ pmin,
                             const float* __restrict__ psec,
                             const int* __restrict__ pidx, int* __restrict__ out,
                             int* __restrict__ list, int* __restrict__ counter) {
  int n = blockIdx.x * 256 + threadIdx.x;
  float v1 = INFINITY, v2 = INFINITY;
  int i1 = 0x7fffffff;
  for (int p = 0; p < 16; ++p) {
    float a1 = pmin[(size_t)p * N_ROWS + n];
    float a2 = psec[(size_t)p * N_ROWS + n];
    int aj = pidx[(size_t)p * N_ROWS + n];
    if (a1 < v1 || (a1 == v1 && aj < i1)) {
      v2 = fminf(v1, a2); v1 = a1; i1 = aj;
    } else {
      v2 = fminf(v2, a1);
    }
  }
  out[n] = i1;
  if (v2 - v1 < TAU) {
    int idx = atomicAdd(counter, 1);
    if (idx < LISTCAP) list[idx] = n;
  }
}

// K5: float64 exact recheck, BATCH-4 rows per block; 32 NAMED f64
// accumulators (rule #20).
#define ACCS(R) \
  double a##R##0 = 0, a##R##1 = 0, a##R##2 = 0, a##R##3 = 0, \
         a##R##4 = 0, a##R##5 = 0, a##R##6 = 0, a##R##7 = 0
#define FMAS(R, XV) \
  a##R##0 = fma(XV, c0, a##R##0); a##R##1 = fma(XV, c1, a##R##1); \
  a##R##2 = fma(XV, c2, a##R##2); a##R##3 = fma(XV, c3, a##R##3); \
  a##R##4 = fma(XV, c4, a##R##4); a##R##5 = fma(XV, c5, a##R##5); \
  a##R##6 = fma(XV, c6, a##R##6); a##R##7 = fma(XV, c7, a##R##7)
#define EVAL(R)                                                         \
  {                                                                     \
    double dots[8] = {a##R##0, a##R##1, a##R##2, a##R##3,               \
                      a##R##4, a##R##5, a##R##6, a##R##7};              \
    double bv = (double)INFINITY;                                       \
    int bi = 0x7fffffff;                                                \
    _Pragma("unroll") for (int j = 0; j < 8; ++j) {                     \
      int k = tid + j * 256;                                            \
      if (k < K_C) {                                                    \
        double dd = (xnorms[R] - 2.0 * dots[j]) + cn64[k];              \
        if (dd < bv) { bv = dd; bi = k; }                               \
      }                                                                 \
    }                                                                   \
    rv[tid] = bv; ri[tid] = bi;                                         \
    __syncthreads();                                                    \
    for (int s = 128; s > 0; s >>= 1) {                                 \
      if (tid < s) {                                                    \
        double ov = rv[tid + s];                                        \
        int oi = ri[tid + s];                                           \
        if (ov < rv[tid] || (ov == rv[tid] && oi < ri[tid])) {          \
          rv[tid] = ov; ri[tid] = oi;                                   \
        }                                                               \
      }                                                                 \
      __syncthreads();                                                  \
    }                                                                   \
    if (tid == 0 && (R) < nrows) out[list[b0 + (R)]] = ri[0];           \
    __syncthreads();                                                    \
  }

__global__ __launch_bounds__(256) void exact_recheck64(
    const float* __restrict__ x, const float* __restrict__ cent,
    const double* __restrict__ cn64, const int* __restrict__ list,
    const int* __restrict__ counter, int* __restrict__ out) {
  __shared__ __align__(16) float xrow[4][DIM];  // 12 KB
  __shared__ double rv[256];
  __shared__ int ri[256];
  __shared__ double xnorms[4];
  int cnt = counter[0];
  if (cnt > LISTCAP) cnt = LISTCAP;
  int b0 = blockIdx.x * 4;
  if (b0 >= cnt) return;
  int nrows = cnt - b0;
  if (nrows > 4) nrows = 4;
  int tid = threadIdx.x;
  for (int r = 0; r < 4; ++r) {
    int n = list[b0 + (r < nrows ? r : 0)];
    double part = 0.0;
    for (int d = tid; d < DIM; d += 256) {
      float v = x[(size_t)n * DIM + d];
      xrow[r][d] = v;
      part += (double)v * (double)v;
    }
    rv[tid] = part;
    __syncthreads();
    for (int s = 128; s > 0; s >>= 1) {
      if (tid < s) rv[tid] += rv[tid + s];
      __syncthreads();
    }
    if (tid == 0) xnorms[r] = rv[0];
    __syncthreads();
  }

  int k7 = tid + 1792;
  int k7c = (k7 < K_C) ? k7 : (K_C - 1);
  ACCS(0); ACCS(1); ACCS(2); ACCS(3);
#pragma unroll 2
  for (int d = 0; d < DIM; ++d) {
    const float* cp = cent + (size_t)d * K_C + tid;
    double c0 = cp[0], c1 = cp[256], c2 = cp[512], c3 = cp[768];
    double c4 = cp[1024], c5 = cp[1280], c6 = cp[1536];
    double c7 = cp[k7c - tid];
    double x0 = xrow[0][d], x1 = xrow[1][d];
    double x2 = xrow[2][d], x3 = xrow[3][d];
    FMAS(0, x0); FMAS(1, x1); FMAS(2, x2); FMAS(3, x3);
  }
  EVAL(0) EVAL(1) EVAL(2) EVAL(3)
}

extern "C" void kernel_launch(void* const* d_in, const int* in_sizes, int n_in,
                              void* d_out, int out_size, void* d_ws, size_t ws_size,
                              hipStream_t stream) {
  const float* x = (const float*)d_in[0];
  const float* cent = (const float*)d_in[1];
  char* ws = (char*)d_ws;
  f16* cTh = (f16*)ws;
  float* cn = (float*)(ws + OFF_CN);
  float* xn = (float*)(ws + OFF_XN);
  float* pmin = (float*)(ws + OFF_PMIN);
  float* psec = (float*)(ws + OFF_PSEC);
  int* pidx = (int*)(ws + OFF_PIDX);
  int* counter = (int*)(ws + OFF_CNT);
  int* list = (int*)(ws + OFF_LIST);
  double* cn64 = (double*)(ws + OFF_CN64);
  f16* xh = (f16*)(ws + OFF_XH);

  hipMemsetAsync(counter, 0, 4, stream);
  prep_cn<<<64, 256, 0, stream>>>(cent, cn, cn64);
  prep_ct<<<dim3(32, 12), 256, 0, stream>>>(cent, cTh);
  xnorm_prepx<<<N_ROWS / 16, 256, 0, stream>>>(x, xn, xh);
  kmeans_main<<<16384, 256, 0, stream>>>(xh, cTh, cn, xn, pmin, psec, pidx);
  merge_detect<<<N_ROWS / 256, 256, 0, stream>>>(pmin, psec, pidx, (int*)d_out,
                                                 list, counter);
  exact_recheck64<<<LISTCAP / 4, 256, 0, stream>>>(x, cent, cn64, list, counter,
                                                   (int*)d_out);
}

// Round 12
// 1127.494 us; speedup vs baseline: 1.4165x; 1.1413x over previous
//
#include <hip/hip_runtime.h>
#include <hip/hip_bf16.h>

#define N_ROWS 131072
#define DIM    768
#define K_C    2000
#define K_PAD  2048
#define TAU    0.2f
#define LISTCAP 8192

typedef _Float16 f16;
typedef _Float16 f16x4 __attribute__((ext_vector_type(4)));
typedef _Float16 f16x8 __attribute__((ext_vector_type(8)));
typedef float    f32x4 __attribute__((ext_vector_type(4)));

// ---- workspace layout (bytes) ----
#define OFF_CN   6291456    // cn   [2048] f32
#define OFF_XN   6299648    // xn   [131072] f32
#define OFF_PMIN 6823936    // pmin [16][131072] f32
#define OFF_PSEC 15212544   // psec [16][131072] f32
#define OFF_PIDX 23601152   // pidx [16][131072] i32
#define OFF_CNT  31989760   // counter
#define OFF_LIST 31990016   // list [8192] i32
#define OFF_CN64 32022784   // cn64 [2048] f64
#define OFF_XH   32039168   // xh [131072][768] f16

static __device__ __forceinline__ void gload16(const void* g, void* l) {
  __builtin_amdgcn_global_load_lds(
      (const __attribute__((address_space(1))) unsigned int*)g,
      (__attribute__((address_space(3))) unsigned int*)l, 16, 0, 0);
}

// K1a: c_norm, 64 blocks x 8-way d-split. Order differs from np —
// acceptable: fp32 cn only feeds gate margins (tau >> order noise);
// fp64 cn64 noise ~1e-13 << true gaps.
__global__ __launch_bounds__(256) void prep_cn(const float* __restrict__ cent,
                                               float* __restrict__ cn,
                                               double* __restrict__ cn64) {
#pragma clang fp contract(off)
  __shared__ float pf[8][32];
  __shared__ double pd[8][32];
  int t = threadIdx.x;
  int kk = t & 31;
  int k = blockIdx.x * 32 + kk;
  int p = t >> 5;
  float s = 0.0f;
  double s64 = 0.0;
  for (int d = p * 96; d < p * 96 + 96; ++d) {
    float c = (k < K_C) ? cent[d * K_C + k] : 0.0f;
    float sq = c * c;
    s = s + sq;
    s64 += (double)c * (double)c;
  }
  pf[p][kk] = s;
  pd[p][kk] = s64;
  __syncthreads();
  if (p == 0) {
    float ss = 0.0f;
    double ss64 = 0.0;
#pragma unroll
    for (int q = 0; q < 8; ++q) {
      ss = ss + pf[q][kk];
      ss64 += pd[q][kk];
    }
    cn[k] = (k < K_C) ? ss : INFINITY;
    cn64[k] = (k < K_C) ? ss64 : (double)INFINITY;
  }
}

// K1b: centroid transpose to f16 via 64x64 LDS tile.
__global__ __launch_bounds__(256) void prep_ct(const float* __restrict__ cent,
                                               f16* __restrict__ cTh) {
  __shared__ float ld[64][65];
  int k0 = blockIdx.x * 64;  // 32 blocks
  int d0 = blockIdx.y * 64;  // 12 blocks
  int tid = threadIdx.x;
#pragma unroll
  for (int it = 0; it < 16; ++it) {
    int idx = it * 256 + tid;
    int dd = idx >> 6, kk = idx & 63;
    int k = k0 + kk;
    ld[dd][kk] = (k < K_C) ? cent[(size_t)(d0 + dd) * K_C + k] : 0.0f;
  }
  __syncthreads();
#pragma unroll
  for (int it = 0; it < 16; ++it) {
    int idx = it * 256 + tid;
    int kk = idx >> 6, dd = idx & 63;
    cTh[(size_t)(k0 + kk) * DIM + d0 + dd] = (f16)ld[dd][kk];
  }
}

// K2: x_norm (numpy FLOAT_pairwise_sum(768) scalar semantics) fused with
// x -> f16.
__global__ __launch_bounds__(256) void xnorm_prepx(const float* __restrict__ x,
                                                   float* __restrict__ xn,
                                                   f16* __restrict__ xh) {
#pragma clang fp contract(off)
  __shared__ __align__(16) float buf[16 * DIM];  // 48 KB, 16 rows
  int row0 = blockIdx.x * 16;
  int tid = threadIdx.x;
  const f32x4* src = (const f32x4*)(x + (size_t)row0 * DIM);
  f32x4* dst = (f32x4*)buf;
#pragma unroll
  for (int c = 0; c < 12; ++c) {
    f32x4 v = src[c * 256 + tid];
    dst[c * 256 + tid] = v;
    f16x4 hv;
#pragma unroll
    for (int j = 0; j < 4; ++j) hv[j] = (f16)v[j];
    *(f16x4*)(xh + (size_t)row0 * DIM + (size_t)(c * 256 + tid) * 4) = hv;
  }
  __syncthreads();
  int w = tid >> 6, lane = tid & 63;
  int b = lane >> 3, j = lane & 7;
#pragma unroll
  for (int rr = 0; rr < 4; ++rr) {
    int r = w * 4 + rr;
    const float* a = buf + r * DIM + 96 * b + j;
    float v0 = a[0];
    float acc = v0 * v0;
#pragma unroll
    for (int t = 1; t < 12; ++t) {
      float q = a[8 * t];
      float s = q * q;
      acc = acc + s;
    }
    float v = acc;
    { float o = __shfl_xor(v, 1);  v = v + o; }
    { float o = __shfl_xor(v, 2);  v = v + o; }
    { float o = __shfl_xor(v, 4);  v = v + o; }
    { float o = __shfl_xor(v, 8);  v = v + o; }
    { float o = __shfl_xor(v, 16); v = v + o; }
    { float o = __shfl_xor(v, 32); v = v + o; }
    if (lane == 0) xn[row0 + r] = v;
  }
}

// K3: f16 MFMA GEMM + fused argmin. TRIPLE-buffered BK=32 pipeline:
// one barrier per K-step AND counted vmcnt(4) (never drained in steady
// state) AND 3 blocks/CU (48 KB LDS). Stage for kt+2 goes into the buffer
// last read at kt-1 (free after this step's barrier: every wave's ds_reads
// complete before its MFMAs, which precede its barrier arrival).
// LDS: A bufs @0/8192/16384; B bufs @24576/+. Linear [128][64B] rows —
// a wave's b128 read covers 64 consecutive 16B granules (4*row+ksel):
// uniform 2-way bank aliasing = free (m136). No swizzle.
#define STAGE3(bufo, ktv)                                                      \
  do {                                                                         \
    _Pragma("unroll") for (int i_ = 0; i_ < 2; ++i_) {                         \
      int c_ = w * 2 + i_;                                                     \
      size_t ga_ = (size_t)(rb * 128 + c_ * 16 + (lane >> 2)) * DIM +          \
                   (ktv) * 32 + (lane & 3) * 8;                                \
      size_t gb_ = (size_t)(pb * 128 + c_ * 16 + (lane >> 2)) * DIM +          \
                   (ktv) * 32 + (lane & 3) * 8;                                \
      gload16(xh + ga_, ldsb + (bufo) + c_ * 1024);                            \
      gload16(cTh + gb_, ldsb + 24576 + (bufo) + c_ * 1024);                   \
    }                                                                          \
  } while (0)

__global__ __launch_bounds__(256, 3) void kmeans_main(
    const f16* __restrict__ xh, const f16* __restrict__ cTh,
    const float* __restrict__ cn, const float* __restrict__ xn,
    float* __restrict__ pmin, float* __restrict__ psec,
    int* __restrict__ pidx) {
  __shared__ __align__(16) f16 lds[24576];  // 48 KiB
  char* ldsb = (char*)lds;

  int d0 = blockIdx.x;
  int g  = (d0 & 7) * 2048 + (d0 >> 3);  // XCD-grouped
  int pb = g & 15;
  int rb = g >> 4;

  int tid  = threadIdx.x;
  int w    = tid >> 6;
  int lane = tid & 63;
  int wrow = (w >> 1) * 64;
  int wcol = (w & 1) * 64;

  int rsel = lane & 15;
  int ksel = lane >> 4;

  f32x4 acc[4][4] = {};

  STAGE3(0, 0);
  STAGE3(8192, 1);

  int cb = 0;       // current buffer offset
  int sb = 16384;   // stage target (buffer of kt+2)
#pragma unroll 3
  for (int kt = 0; kt < 24; ++kt) {
    if (kt < 23) {
      asm volatile("s_waitcnt vmcnt(4)" ::: "memory");  // tile kt landed;
                                                        // kt+1 stays in flight
    } else {
      asm volatile("s_waitcnt vmcnt(0)" ::: "memory");
    }
    __builtin_amdgcn_sched_barrier(0);
    __builtin_amdgcn_s_barrier();
    __builtin_amdgcn_sched_barrier(0);

    if (kt < 22) STAGE3(sb, kt + 2);  // into buffer freed at kt-1

    f16x8 ah[4], bh[4];
    int abase = cb + (wrow + rsel) * 64 + ksel * 16;
    int bbase = cb + 24576 + (wcol + rsel) * 64 + ksel * 16;
#pragma unroll
    for (int m = 0; m < 4; ++m) ah[m] = *(const f16x8*)(ldsb + abase + m * 1024);
#pragma unroll
    for (int n = 0; n < 4; ++n) bh[n] = *(const f16x8*)(ldsb + bbase + n * 1024);

    // no manual lgkmcnt wall: compiler interleaves ds_read completion
    // with the MFMA chain via fine-grained lgkmcnt(N)
    __builtin_amdgcn_s_setprio(1);
#pragma unroll
    for (int m = 0; m < 4; ++m)
#pragma unroll
      for (int n = 0; n < 4; ++n)
        acc[m][n] = __builtin_amdgcn_mfma_f32_16x16x32_f16(ah[m], bh[n],
                                                           acc[m][n], 0, 0, 0);
    __builtin_amdgcn_s_setprio(0);

    cb = (cb == 16384) ? 0 : cb + 8192;
    sb = (sb == 16384) ? 0 : sb + 8192;
  }

  __syncthreads();  // drain; LDS reused below
  float* lv = (float*)lds;                 // [2][128]
  float* lsv = (float*)lds + 256;          // [2][128]
  int*   li = (int*)((float*)lds + 512);   // [2][128]

  int colbase = pb * 128 + wcol + rsel;
  float cnv[4];
#pragma unroll
  for (int n = 0; n < 4; ++n) cnv[n] = cn[colbase + n * 16];
  int g4 = ksel * 4;

#pragma unroll
  for (int m = 0; m < 4; ++m) {
#pragma unroll
    for (int j = 0; j < 4; ++j) {
      int trow = wrow + m * 16 + g4 + j;
      float xv = xn[rb * 128 + trow];
      float v1 = 0.0f, v2 = INFINITY;
      int i1 = 0;
#pragma unroll
      for (int n = 0; n < 4; ++n) {
        float dd = (xv - 2.0f * acc[m][n][j]) + cnv[n];
        int ci = colbase + n * 16;
        if (n == 0) { v1 = dd; i1 = ci; }
        else if (dd < v1) { v2 = v1; v1 = dd; i1 = ci; }
        else { v2 = fminf(v2, dd); }
      }
#pragma unroll
      for (int off = 1; off < 16; off <<= 1) {
        float ov1 = __shfl_xor(v1, off);
        float ov2 = __shfl_xor(v2, off);
        int oi1 = __shfl_xor(i1, off);
        if (ov1 < v1 || (ov1 == v1 && oi1 < i1)) {
          v2 = fminf(v1, ov2); v1 = ov1; i1 = oi1;
        } else {
          v2 = fminf(v2, ov1);
        }
      }
      if ((lane & 15) == 0) {
        lv[(w & 1) * 128 + trow] = v1;
        lsv[(w & 1) * 128 + trow] = v2;
        li[(w & 1) * 128 + trow] = i1;
      }
    }
  }
  __syncthreads();
  if (tid < 128) {
    float a1 = lv[tid], a2 = lsv[tid];
    int aj = li[tid];
    float b1 = lv[128 + tid], b2 = lsv[128 + tid];
    int bj = li[128 + tid];
    float v1, v2; int i1;
    if (b1 < a1 || (b1 == a1 && bj < aj)) { v1 = b1; i1 = bj; v2 = fminf(b2, a1); }
    else { v1 = a1; i1 = aj; v2 = fminf(a2, b1); }
    size_t o = (size_t)pb * N_ROWS + rb * 128 + tid;
    pmin[o] = v1;
    psec[o] = v2;
    pidx[o] = i1;
  }
}

// K4: merge 16 panel triples; flag ambiguous rows (margin < TAU).
__global__ void merge_detect(const float* __restrict__ pmin,
                             const float* __restrict__ psec,
                             const int* __restrict__ pidx, int* __restrict__ out,
                             int* __restrict__ list, int* __restrict__ counter) {
  int n = blockIdx.x * 256 + threadIdx.x;
  float v1 = INFINITY, v2 = INFINITY;
  int i1 = 0x7fffffff;
  for (int p = 0; p < 16; ++p) {
    float a1 = pmin[(size_t)p * N_ROWS + n];
    float a2 = psec[(size_t)p * N_ROWS + n];
    int aj = pidx[(size_t)p * N_ROWS + n];
    if (a1 < v1 || (a1 == v1 && aj < i1)) {
      v2 = fminf(v1, a2); v1 = a1; i1 = aj;
    } else {
      v2 = fminf(v2, a1);
    }
  }
  out[n] = i1;
  if (v2 - v1 < TAU) {
    int idx = atomicAdd(counter, 1);
    if (idx < LISTCAP) list[idx] = n;
  }
}

// K5: float64 exact recheck, BATCH-4 rows per block; 32 NAMED f64
// accumulators (rule #20).
#define ACCS(R) \
  double a##R##0 = 0, a##R##1 = 0, a##R##2 = 0, a##R##3 = 0, \
         a##R##4 = 0, a##R##5 = 0, a##R##6 = 0, a##R##7 = 0
#define FMAS(R, XV) \
  a##R##0 = fma(XV, c0, a##R##0); a##R##1 = fma(XV, c1, a##R##1); \
  a##R##2 = fma(XV, c2, a##R##2); a##R##3 = fma(XV, c3, a##R##3); \
  a##R##4 = fma(XV, c4, a##R##4); a##R##5 = fma(XV, c5, a##R##5); \
  a##R##6 = fma(XV, c6, a##R##6); a##R##7 = fma(XV, c7, a##R##7)
#define EVAL(R)                                                         \
  {                                                                     \
    double dots[8] = {a##R##0, a##R##1, a##R##2, a##R##3,               \
                      a##R##4, a##R##5, a##R##6, a##R##7};              \
    double bv = (double)INFINITY;                                       \
    int bi = 0x7fffffff;                                                \
    _Pragma("unroll") for (int j = 0; j < 8; ++j) {                     \
      int k = tid + j * 256;                                            \
      if (k < K_C) {                                                    \
        double dd = (xnorms[R] - 2.0 * dots[j]) + cn64[k];              \
        if (dd < bv) { bv = dd; bi = k; }                               \
      }                                                                 \
    }                                                                   \
    rv[tid] = bv; ri[tid] = bi;                                         \
    __syncthreads();                                                    \
    for (int s = 128; s > 0; s >>= 1) {                                 \
      if (tid < s) {                                                    \
        double ov = rv[tid + s];                                        \
        int oi = ri[tid + s];                                           \
        if (ov < rv[tid] || (ov == rv[tid] && oi < ri[tid])) {          \
          rv[tid] = ov; ri[tid] = oi;                                   \
        }                                                               \
      }                                                                 \
      __syncthreads();                                                  \
    }                                                                   \
    if (tid == 0 && (R) < nrows) out[list[b0 + (R)]] = ri[0];           \
    __syncthreads();                                                    \
  }

__global__ __launch_bounds__(256) void exact_recheck64(
    const float* __restrict__ x, const float* __restrict__ cent,
    const double* __restrict__ cn64, const int* __restrict__ list,
    const int* __restrict__ counter, int* __restrict__ out) {
  __shared__ __align__(16) float xrow[4][DIM];  // 12 KB
  __shared__ double rv[256];
  __shared__ int ri[256];
  __shared__ double xnorms[4];
  int cnt = counter[0];
  if (cnt > LISTCAP) cnt = LISTCAP;
  int b0 = blockIdx.x * 4;
  if (b0 >= cnt) return;
  int nrows = cnt - b0;
  if (nrows > 4) nrows = 4;
  int tid = threadIdx.x;
  for (int r = 0; r < 4; ++r) {
    int n = list[b0 + (r < nrows ? r : 0)];
    double part = 0.0;
    for (int d = tid; d < DIM; d += 256) {
      float v = x[(size_t)n * DIM + d];
      xrow[r][d] = v;
      part += (double)v * (double)v;
    }
    rv[tid] = part;
    __syncthreads();
    for (int s = 128; s > 0; s >>= 1) {
      if (tid < s) rv[tid] += rv[tid + s];
      __syncthreads();
    }
    if (tid == 0) xnorms[r] = rv[0];
    __syncthreads();
  }

  int k7 = tid + 1792;
  int k7c = (k7 < K_C) ? k7 : (K_C - 1);
  ACCS(0); ACCS(1); ACCS(2); ACCS(3);
#pragma unroll 2
  for (int d = 0; d < DIM; ++d) {
    const float* cp = cent + (size_t)d * K_C + tid;
    double c0 = cp[0], c1 = cp[256], c2 = cp[512], c3 = cp[768];
    double c4 = cp[1024], c5 = cp[1280], c6 = cp[1536];
    double c7 = cp[k7c - tid];
    double x0 = xrow[0][d], x1 = xrow[1][d];
    double x2 = xrow[2][d], x3 = xrow[3][d];
    FMAS(0, x0); FMAS(1, x1); FMAS(2, x2); FMAS(3, x3);
  }
  EVAL(0) EVAL(1) EVAL(2) EVAL(3)
}

extern "C" void kernel_launch(void* const* d_in, const int* in_sizes, int n_in,
                              void* d_out, int out_size, void* d_ws, size_t ws_size,
                              hipStream_t stream) {
  const float* x = (const float*)d_in[0];
  const float* cent = (const float*)d_in[1];
  char* ws = (char*)d_ws;
  f16* cTh = (f16*)ws;
  float* cn = (float*)(ws + OFF_CN);
  float* xn = (float*)(ws + OFF_XN);
  float* pmin = (float*)(ws + OFF_PMIN);
  float* psec = (float*)(ws + OFF_PSEC);
  int* pidx = (int*)(ws + OFF_PIDX);
  int* counter = (int*)(ws + OFF_CNT);
  int* list = (int*)(ws + OFF_LIST);
  double* cn64 = (double*)(ws + OFF_CN64);
  f16* xh = (f16*)(ws + OFF_XH);

  hipMemsetAsync(counter, 0, 4, stream);
  prep_cn<<<64, 256, 0, stream>>>(cent, cn, cn64);
  prep_ct<<<dim3(32, 12), 256, 0, stream>>>(cent, cTh);
  xnorm_prepx<<<N_ROWS / 16, 256, 0, stream>>>(x, xn, xh);
  kmeans_main<<<16384, 256, 0, stream>>>(xh, cTh, cn, xn, pmin, psec, pidx);
  merge_detect<<<N_ROWS / 256, 256, 0, stream>>>(pmin, psec, pidx, (int*)d_out,
                                                 list, counter);
  exact_recheck64<<<LISTCAP / 4, 256, 0, stream>>>(x, cent, cn64, list, counter,
                                                   (int*)d_out);
}

// Round 13
// 1098.413 us; speedup vs baseline: 1.4540x; 1.0265x over previous
//
#include <hip/hip_runtime.h>
#include <hip/hip_bf16.h>

#define N_ROWS 131072
#define DIM    768
#define K_C    2000
#define K_PAD  2048
#define TAU    0.2f
#define LISTCAP 8192

typedef _Float16 f16;
typedef _Float16 f16x4 __attribute__((ext_vector_type(4)));
typedef _Float16 f16x8 __attribute__((ext_vector_type(8)));
typedef float    f32x4 __attribute__((ext_vector_type(4)));

// ---- workspace layout (bytes) ----
#define OFF_CN   6291456    // cn   [2048] f32
#define OFF_XN   6299648    // xn   [131072] f32
#define OFF_PMIN 6823936    // pmin [16][131072] f32
#define OFF_PSEC 15212544   // psec [16][131072] f32
#define OFF_PIDX 23601152   // pidx [16][131072] i32
#define OFF_CNT  31989760   // counter
#define OFF_LIST 31990016   // list [8192] i32
#define OFF_CN64 32022784   // cn64 [2048] f64
#define OFF_XH   32039168   // xh [131072][768] f16

static __device__ __forceinline__ void gload16(const void* g, void* l) {
  __builtin_amdgcn_global_load_lds(
      (const __attribute__((address_space(1))) unsigned int*)g,
      (__attribute__((address_space(3))) unsigned int*)l, 16, 0, 0);
}

// K1a: c_norm, 64 blocks x 8-way d-split. Order differs from np —
// acceptable: fp32 cn only feeds gate margins (tau >> order noise);
// fp64 cn64 noise ~1e-13 << true gaps.
__global__ __launch_bounds__(256) void prep_cn(const float* __restrict__ cent,
                                               float* __restrict__ cn,
                                               double* __restrict__ cn64) {
#pragma clang fp contract(off)
  __shared__ float pf[8][32];
  __shared__ double pd[8][32];
  int t = threadIdx.x;
  int kk = t & 31;
  int k = blockIdx.x * 32 + kk;
  int p = t >> 5;
  float s = 0.0f;
  double s64 = 0.0;
  for (int d = p * 96; d < p * 96 + 96; ++d) {
    float c = (k < K_C) ? cent[d * K_C + k] : 0.0f;
    float sq = c * c;
    s = s + sq;
    s64 += (double)c * (double)c;
  }
  pf[p][kk] = s;
  pd[p][kk] = s64;
  __syncthreads();
  if (p == 0) {
    float ss = 0.0f;
    double ss64 = 0.0;
#pragma unroll
    for (int q = 0; q < 8; ++q) {
      ss = ss + pf[q][kk];
      ss64 += pd[q][kk];
    }
    cn[k] = (k < K_C) ? ss : INFINITY;
    cn64[k] = (k < K_C) ? ss64 : (double)INFINITY;
  }
}

// K1b: centroid transpose to f16 via 64x64 LDS tile.
__global__ __launch_bounds__(256) void prep_ct(const float* __restrict__ cent,
                                               f16* __restrict__ cTh) {
  __shared__ float ld[64][65];
  int k0 = blockIdx.x * 64;  // 32 blocks
  int d0 = blockIdx.y * 64;  // 12 blocks
  int tid = threadIdx.x;
#pragma unroll
  for (int it = 0; it < 16; ++it) {
    int idx = it * 256 + tid;
    int dd = idx >> 6, kk = idx & 63;
    int k = k0 + kk;
    ld[dd][kk] = (k < K_C) ? cent[(size_t)(d0 + dd) * K_C + k] : 0.0f;
  }
  __syncthreads();
#pragma unroll
  for (int it = 0; it < 16; ++it) {
    int idx = it * 256 + tid;
    int kk = idx >> 6, dd = idx & 63;
    cTh[(size_t)(k0 + kk) * DIM + d0 + dd] = (f16)ld[dd][kk];
  }
}

// K2: x_norm (numpy FLOAT_pairwise_sum(768) scalar semantics) fused with
// x -> f16.
__global__ __launch_bounds__(256) void xnorm_prepx(const float* __restrict__ x,
                                                   float* __restrict__ xn,
                                                   f16* __restrict__ xh) {
#pragma clang fp contract(off)
  __shared__ __align__(16) float buf[16 * DIM];  // 48 KB, 16 rows
  int row0 = blockIdx.x * 16;
  int tid = threadIdx.x;
  const f32x4* src = (const f32x4*)(x + (size_t)row0 * DIM);
  f32x4* dst = (f32x4*)buf;
#pragma unroll
  for (int c = 0; c < 12; ++c) {
    f32x4 v = src[c * 256 + tid];
    dst[c * 256 + tid] = v;
    f16x4 hv;
#pragma unroll
    for (int j = 0; j < 4; ++j) hv[j] = (f16)v[j];
    *(f16x4*)(xh + (size_t)row0 * DIM + (size_t)(c * 256 + tid) * 4) = hv;
  }
  __syncthreads();
  int w = tid >> 6, lane = tid & 63;
  int b = lane >> 3, j = lane & 7;
#pragma unroll
  for (int rr = 0; rr < 4; ++rr) {
    int r = w * 4 + rr;
    const float* a = buf + r * DIM + 96 * b + j;
    float v0 = a[0];
    float acc = v0 * v0;
#pragma unroll
    for (int t = 1; t < 12; ++t) {
      float q = a[8 * t];
      float s = q * q;
      acc = acc + s;
    }
    float v = acc;
    { float o = __shfl_xor(v, 1);  v = v + o; }
    { float o = __shfl_xor(v, 2);  v = v + o; }
    { float o = __shfl_xor(v, 4);  v = v + o; }
    { float o = __shfl_xor(v, 8);  v = v + o; }
    { float o = __shfl_xor(v, 16); v = v + o; }
    { float o = __shfl_xor(v, 32); v = v + o; }
    if (lane == 0) xn[row0 + r] = v;
  }
}

// K3: f16 MFMA GEMM + fused argmin. Triple-buffered BK=32 (r12) +
// GRANULE SWIZZLE fixing r12's 4-way bank conflict (5e7 measured):
// physical slot s at row r holds logical k-granule s ^ ((r>>1)&3).
// Stage side: global source granule g = (lane&3) ^ ((lane>>3)&3)
// (within-chunk row = lane>>2). Read side: rs = (ksel ^ ((rsel>>1)&3))<<4.
// Any 8 consecutive lanes now hit all 32 banks exactly once.
// Staging addresses hoisted into 4 per-lane pointers (+=64 B/step).
#define STAGE3(bufo)                                                           \
  do {                                                                         \
    gload16(pA0, ldsb + (bufo) + c0 * 1024);                                   \
    gload16(pA1, ldsb + (bufo) + c1 * 1024);                                   \
    gload16(pB0, ldsb + 24576 + (bufo) + c0 * 1024);                           \
    gload16(pB1, ldsb + 24576 + (bufo) + c1 * 1024);                           \
    pA0 += 64; pA1 += 64; pB0 += 64; pB1 += 64;                                \
  } while (0)

__global__ __launch_bounds__(256, 3) void kmeans_main(
    const f16* __restrict__ xh, const f16* __restrict__ cTh,
    const float* __restrict__ cn, const float* __restrict__ xn,
    float* __restrict__ pmin, float* __restrict__ psec,
    int* __restrict__ pidx) {
  __shared__ __align__(16) f16 lds[24576];  // 48 KiB
  char* ldsb = (char*)lds;

  int d0 = blockIdx.x;
  int g  = (d0 & 7) * 2048 + (d0 >> 3);  // XCD-grouped
  int pb = g & 15;
  int rb = g >> 4;

  int tid  = threadIdx.x;
  int w    = tid >> 6;
  int lane = tid & 63;
  int wrow = (w >> 1) * 64;
  int wcol = (w & 1) * 64;

  int rsel = lane & 15;
  int ksel = lane >> 4;
  int rs = (ksel ^ ((rsel >> 1) & 3)) << 4;  // swizzled granule byte-offset

  // staging constants: chunk = 1 KB = 16 rows x 64 B; this wave's chunks
  int c0 = w * 2, c1 = w * 2 + 1;
  int grn = (lane & 3) ^ ((lane >> 3) & 3);  // inverse-swizzled src granule
  const char* pA0 = (const char*)xh +
      ((size_t)(rb * 128 + c0 * 16 + (lane >> 2)) * DIM + grn * 8) * 2;
  const char* pA1 = (const char*)xh +
      ((size_t)(rb * 128 + c1 * 16 + (lane >> 2)) * DIM + grn * 8) * 2;
  const char* pB0 = (const char*)cTh +
      ((size_t)(pb * 128 + c0 * 16 + (lane >> 2)) * DIM + grn * 8) * 2;
  const char* pB1 = (const char*)cTh +
      ((size_t)(pb * 128 + c1 * 16 + (lane >> 2)) * DIM + grn * 8) * 2;

  f32x4 acc[4][4] = {};

  STAGE3(0);
  STAGE3(8192);

  int cb = 0;       // current buffer offset
  int sb = 16384;   // stage target (buffer of kt+2)
#pragma unroll 3
  for (int kt = 0; kt < 24; ++kt) {
    if (kt < 23) {
      asm volatile("s_waitcnt vmcnt(4)" ::: "memory");  // tile kt landed;
                                                        // kt+1 stays in flight
    } else {
      asm volatile("s_waitcnt vmcnt(0)" ::: "memory");
    }
    __builtin_amdgcn_sched_barrier(0);
    __builtin_amdgcn_s_barrier();
    __builtin_amdgcn_sched_barrier(0);

    if (kt < 22) STAGE3(sb);  // into buffer freed at kt-1

    f16x8 ah[4], bh[4];
    int abase = cb + (wrow + rsel) * 64 + rs;
    int bbase = cb + 24576 + (wcol + rsel) * 64 + rs;
#pragma unroll
    for (int m = 0; m < 4; ++m) ah[m] = *(const f16x8*)(ldsb + abase + m * 1024);
#pragma unroll
    for (int n = 0; n < 4; ++n) bh[n] = *(const f16x8*)(ldsb + bbase + n * 1024);

    // no manual lgkmcnt wall: compiler interleaves ds_read completion
    // with the MFMA chain via fine-grained lgkmcnt(N)
    __builtin_amdgcn_s_setprio(1);
#pragma unroll
    for (int m = 0; m < 4; ++m)
#pragma unroll
      for (int n = 0; n < 4; ++n)
        acc[m][n] = __builtin_amdgcn_mfma_f32_16x16x32_f16(ah[m], bh[n],
                                                           acc[m][n], 0, 0, 0);
    __builtin_amdgcn_s_setprio(0);

    cb = (cb == 16384) ? 0 : cb + 8192;
    sb = (sb == 16384) ? 0 : sb + 8192;
  }

  __syncthreads();  // drain; LDS reused below
  float* lv = (float*)lds;                 // [2][128]
  float* lsv = (float*)lds + 256;          // [2][128]
  int*   li = (int*)((float*)lds + 512);   // [2][128]

  int colbase = pb * 128 + wcol + rsel;
  float cnv[4];
#pragma unroll
  for (int n = 0; n < 4; ++n) cnv[n] = cn[colbase + n * 16];
  int g4 = ksel * 4;

#pragma unroll
  for (int m = 0; m < 4; ++m) {
#pragma unroll
    for (int j = 0; j < 4; ++j) {
      int trow = wrow + m * 16 + g4 + j;
      float xv = xn[rb * 128 + trow];
      float v1 = 0.0f, v2 = INFINITY;
      int i1 = 0;
#pragma unroll
      for (int n = 0; n < 4; ++n) {
        float dd = (xv - 2.0f * acc[m][n][j]) + cnv[n];
        int ci = colbase + n * 16;
        if (n == 0) { v1 = dd; i1 = ci; }
        else if (dd < v1) { v2 = v1; v1 = dd; i1 = ci; }
        else { v2 = fminf(v2, dd); }
      }
#pragma unroll
      for (int off = 1; off < 16; off <<= 1) {
        float ov1 = __shfl_xor(v1, off);
        float ov2 = __shfl_xor(v2, off);
        int oi1 = __shfl_xor(i1, off);
        if (ov1 < v1 || (ov1 == v1 && oi1 < i1)) {
          v2 = fminf(v1, ov2); v1 = ov1; i1 = oi1;
        } else {
          v2 = fminf(v2, ov1);
        }
      }
      if ((lane & 15) == 0) {
        lv[(w & 1) * 128 + trow] = v1;
        lsv[(w & 1) * 128 + trow] = v2;
        li[(w & 1) * 128 + trow] = i1;
      }
    }
  }
  __syncthreads();
  if (tid < 128) {
    float a1 = lv[tid], a2 = lsv[tid];
    int aj = li[tid];
    float b1 = lv[128 + tid], b2 = lsv[128 + tid];
    int bj = li[128 + tid];
    float v1, v2; int i1;
    if (b1 < a1 || (b1 == a1 && bj < aj)) { v1 = b1; i1 = bj; v2 = fminf(b2, a1); }
    else { v1 = a1; i1 = aj; v2 = fminf(a2, b1); }
    size_t o = (size_t)pb * N_ROWS + rb * 128 + tid;
    pmin[o] = v1;
    psec[o] = v2;
    pidx[o] = i1;
  }
}

// K4: merge 16 panel triples; flag ambiguous rows (margin < TAU).
__global__ void merge_detect(const float* __restrict__ pmin,
                             const float* __restrict__ psec,
                             const int* __restrict__ pidx, int* __restrict__ out,
                             int* __restrict__ list, int* __restrict__ counter) {
  int n = blockIdx.x * 256 + threadIdx.x;
  float v1 = INFINITY, v2 = INFINITY;
  int i1 = 0x7fffffff;
  for (int p = 0; p < 16; ++p) {
    float a1 = pmin[(size_t)p * N_ROWS + n];
    float a2 = psec[(size_t)p * N_ROWS + n];
    int aj = pidx[(size_t)p * N_ROWS + n];
    if (a1 < v1 || (a1 == v1 && aj < i1)) {
      v2 = fminf(v1, a2); v1 = a1; i1 = aj;
    } else {
      v2 = fminf(v2, a1);
    }
  }
  out[n] = i1;
  if (v2 - v1 < TAU) {
    int idx = atomicAdd(counter, 1);
    if (idx < LISTCAP) list[idx] = n;
  }
}

// K5: float64 exact recheck, BATCH-4 rows per block; 32 NAMED f64
// accumulators (rule #20).
#define ACCS(R) \
  double a##R##0 = 0, a##R##1 = 0, a##R##2 = 0, a##R##3 = 0, \
         a##R##4 = 0, a##R##5 = 0, a##R##6 = 0, a##R##7 = 0
#define FMAS(R, XV) \
  a##R##0 = fma(XV, c0, a##R##0); a##R##1 = fma(XV, c1, a##R##1); \
  a##R##2 = fma(XV, c2, a##R##2); a##R##3 = fma(XV, c3, a##R##3); \
  a##R##4 = fma(XV, c4, a##R##4); a##R##5 = fma(XV, c5, a##R##5); \
  a##R##6 = fma(XV, c6, a##R##6); a##R##7 = fma(XV, c7, a##R##7)
#define EVAL(R)                                                         \
  {                                                                     \
    double dots[8] = {a##R##0, a##R##1, a##R##2, a##R##3,               \
                      a##R##4, a##R##5, a##R##6, a##R##7};              \
    double bv = (double)INFINITY;                                       \
    int bi = 0x7fffffff;                                                \
    _Pragma("unroll") for (int j = 0; j < 8; ++j) {                     \
      int k = tid + j * 256;                                            \
      if (k < K_C) {                                                    \
        double dd = (xnorms[R] - 2.0 * dots[j]) + cn64[k];              \
        if (dd < bv) { bv = dd; bi = k; }                               \
      }                                                                 \
    }                                                                   \
    rv[tid] = bv; ri[tid] = bi;                                         \
    __syncthreads();                                                    \
    for (int s = 128; s > 0; s >>= 1) {                                 \
      if (tid < s) {                                                    \
        double ov = rv[tid + s];                                        \
        int oi = ri[tid + s];                                           \
        if (ov < rv[tid] || (ov == rv[tid] && oi < ri[tid])) {          \
          rv[tid] = ov; ri[tid] = oi;                                   \
        }                                                               \
      }                                                                 \
      __syncthreads();                                                  \
    }                                                                   \
    if (tid == 0 && (R) < nrows) out[list[b0 + (R)]] = ri[0];           \
    __syncthreads();                                                    \
  }

__global__ __launch_bounds__(256) void exact_recheck64(
    const float* __restrict__ x, const float* __restrict__ cent,
    const double* __restrict__ cn64, const int* __restrict__ list,
    const int* __restrict__ counter, int* __restrict__ out) {
  __shared__ __align__(16) float xrow[4][DIM];  // 12 KB
  __shared__ double rv[256];
  __shared__ int ri[256];
  __shared__ double xnorms[4];
  int cnt = counter[0];
  if (cnt > LISTCAP) cnt = LISTCAP;
  int b0 = blockIdx.x * 4;
  if (b0 >= cnt) return;
  int nrows = cnt - b0;
  if (nrows > 4) nrows = 4;
  int tid = threadIdx.x;
  for (int r = 0; r < 4; ++r) {
    int n = list[b0 + (r < nrows ? r : 0)];
    double part = 0.0;
    for (int d = tid; d < DIM; d += 256) {
      float v = x[(size_t)n * DIM + d];
      xrow[r][d] = v;
      part += (double)v * (double)v;
    }
    rv[tid] = part;
    __syncthreads();
    for (int s = 128; s > 0; s >>= 1) {
      if (tid < s) rv[tid] += rv[tid + s];
      __syncthreads();
    }
    if (tid == 0) xnorms[r] = rv[0];
    __syncthreads();
  }

  int k7 = tid + 1792;
  int k7c = (k7 < K_C) ? k7 : (K_C - 1);
  ACCS(0); ACCS(1); ACCS(2); ACCS(3);
#pragma unroll 2
  for (int d = 0; d < DIM; ++d) {
    const float* cp = cent + (size_t)d * K_C + tid;
    double c0 = cp[0], c1 = cp[256], c2 = cp[512], c3 = cp[768];
    double c4 = cp[1024], c5 = cp[1280], c6 = cp[1536];
    double c7 = cp[k7c - tid];
    double x0 = xrow[0][d], x1 = xrow[1][d];
    double x2 = xrow[2][d], x3 = xrow[3][d];
    FMAS(0, x0); FMAS(1, x1); FMAS(2, x2); FMAS(3, x3);
  }
  EVAL(0) EVAL(1) EVAL(2) EVAL(3)
}

extern "C" void kernel_launch(void* const* d_in, const int* in_sizes, int n_in,
                              void* d_out, int out_size, void* d_ws, size_t ws_size,
                              hipStream_t stream) {
  const float* x = (const float*)d_in[0];
  const float* cent = (const float*)d_in[1];
  char* ws = (char*)d_ws;
  f16* cTh = (f16*)ws;
  float* cn = (float*)(ws + OFF_CN);
  float* xn = (float*)(ws + OFF_XN);
  float* pmin = (float*)(ws + OFF_PMIN);
  float* psec = (float*)(ws + OFF_PSEC);
  int* pidx = (int*)(ws + OFF_PIDX);
  int* counter = (int*)(ws + OFF_CNT);
  int* list = (int*)(ws + OFF_LIST);
  double* cn64 = (double*)(ws + OFF_CN64);
  f16* xh = (f16*)(ws + OFF_XH);

  hipMemsetAsync(counter, 0, 4, stream);
  prep_cn<<<64, 256, 0, stream>>>(cent, cn, cn64);
  prep_ct<<<dim3(32, 12), 256, 0, stream>>>(cent, cTh);
  xnorm_prepx<<<N_ROWS / 16, 256, 0, stream>>>(x, xn, xh);
  kmeans_main<<<16384, 256, 0, stream>>>(xh, cTh, cn, xn, pmin, psec, pidx);
  merge_detect<<<N_ROWS / 256, 256, 0, stream>>>(pmin, psec, pidx, (int*)d_out,
                                                 list, counter);
  exact_recheck64<<<LISTCAP / 4, 256, 0, stream>>>(x, cent, cn64, list, counter,
                                                   (int*)d_out);
}